// Round 4
// baseline (294.943 us; speedup 1.0000x reference)
//
#include <hip/hip_runtime.h>
#include <hip/hip_fp16.h>

// COO SpMM: out[row[e], :] += values[e] * b[col[e], :]
// N=100000, E=1600000, D=128, fp32.
// v10: row-granular binning eliminates phase2's sort entirely.
//   - phase1_rows: single-pass grid-stride; packed[r*capr + atomicAdd(row_cnt[r])]
//     (1.6M atomics over 100K counters, ~16 increments each -> low contention)
//   - phase2_rows: no LDS, no barriers. 32-lane group per row: uniform
//     broadcast read of the row's edge list + 256B fp16 gather per edge.
//     v7's phase2 was latency-bound (48% occ, 34% VALU) on its LDS-sort
//     prologue + 12-barrier scan, not on gather traffic.
//   - v9's D-slicing reverted (FETCH unchanged, WRITE 3x, LDS conflicts 15x).
//   - exact v7 bucket-sort path kept as fallback when ws can't hold the
//     row layout (needs ~52MB at capr=32 vs v7's ~43.5MB).

#define D_DIM 128
#define RPB 64            // rows per bucket (v7 fallback path)
#define RPB_SHIFT 6
#define MAXB 2048         // phase1 LDS histogram capacity (N <= 131072)
#define CAP_LDS 1408      // max edges per bucket in phase2 LDS (avg ~1023)
#define EPT 6             // phase2: ceil(CAP_LDS/256) edges/thread in regs
#define EPT1 8            // phase1: cached edges/thread (chunk <= 8192)
#define OVF_MAX 65536
#define CAPR_MIN 28       // row path: Poisson(16) overflow ~2e-3/row at 28
#define CAPR_MAX 40       // Poisson(16) overflow ~1e-7/row at 40

typedef float fx4 __attribute__((ext_vector_type(4)));

// ---------------- b -> fp16 conversion (row-major, shared) ----------------
__global__ __launch_bounds__(256) void convert_b_kernel(
        const float* __restrict__ b, __half* __restrict__ bh, int n8) {
    int i = blockIdx.x * blockDim.x + threadIdx.x;
    if (i >= n8) return;
    const float4* b4 = (const float4*)b;
    float4 a0 = b4[2 * i];
    float4 a1 = b4[2 * i + 1];
    union { __half2 h[4]; uint4 u; } pk;
    pk.h[0] = __floats2half2_rn(a0.x, a0.y);
    pk.h[1] = __floats2half2_rn(a0.z, a0.w);
    pk.h[2] = __floats2half2_rn(a1.x, a1.y);
    pk.h[3] = __floats2half2_rn(a1.z, a1.w);
    ((uint4*)bh)[i] = pk.u;
}

// ================= ROW-DIRECT PATH =================

// phase 1: bin edges at row granularity, single pass
__global__ __launch_bounds__(256) void phase1_rows(
        const int* __restrict__ rows,
        const int* __restrict__ cols,
        const float* __restrict__ vals,
        int* __restrict__ row_cnt,
        int2* __restrict__ packed,
        int* __restrict__ ovf_cnt,
        int* __restrict__ ovf_list,
        int E, int capr) {
    int idx = blockIdx.x * 256 + threadIdx.x;
    int stride = gridDim.x * 256;
    for (int e = idx; e < E; e += stride) {
        int r = rows[e];
        int c = cols[e];
        float v = vals[e];
        int local = atomicAdd(&row_cnt[r], 1);
        if (local < capr) {
            packed[(size_t)r * capr + local] = make_int2(c, __float_as_int(v));
        } else {
            int k = atomicAdd(ovf_cnt, 1);
            if (k < OVF_MAX) ovf_list[k] = e;
        }
    }
}

// phase 2: no LDS, no barriers. One 32-lane group per row; 8 rows per block.
template <bool HALF>
__global__ __launch_bounds__(256) void phase2_rows(
        const int* __restrict__ row_cnt,
        const int2* __restrict__ packed,
        const __half* __restrict__ bh,
        const float* __restrict__ b,
        float* __restrict__ out,
        int capr, int N) {
    int g = threadIdx.x >> 5;        // group 0..7
    int glane = threadIdx.x & 31;
    int r = blockIdx.x * 8 + g;
    if (r >= N) return;

    int cnt = row_cnt[r];
    if (cnt > capr) cnt = capr;
    const int2* pk = packed + (size_t)r * capr;

    float4 acc = make_float4(0.f, 0.f, 0.f, 0.f);
    for (int base = 0; base < cnt; base += 8) {
#pragma unroll
        for (int j = 0; j < 8; ++j) {
            int idx = base + j;
            int sidx = (idx < cnt) ? idx : (cnt - 1);
            int2 e = pk[sidx];                 // uniform within group: broadcast
            float v = (idx < cnt) ? __int_as_float(e.y) : 0.f;
            if (HALF) {
                uint2 hv = ((const uint2*)(bh + (size_t)e.x * D_DIM))[glane];
                __half2* hp = (__half2*)&hv;
                float2 f0 = __half22float2(hp[0]);
                float2 f1 = __half22float2(hp[1]);
                acc.x += v * f0.x;
                acc.y += v * f0.y;
                acc.z += v * f1.x;
                acc.w += v * f1.y;
            } else {
                float4 bv = ((const float4*)(b + (size_t)e.x * D_DIM))[glane];
                acc.x += v * bv.x;
                acc.y += v * bv.y;
                acc.z += v * bv.z;
                acc.w += v * bv.w;
            }
        }
    }
    fx4 av = {acc.x, acc.y, acc.z, acc.w};
    __builtin_nontemporal_store(av, (fx4*)(out + (size_t)r * D_DIM) + glane);
}

// ================= V7 BUCKET-SORT PATH (fallback, verbatim) =================

__global__ __launch_bounds__(1024) void phase1_partition(
        const int* __restrict__ rows,
        const int* __restrict__ cols,
        const float* __restrict__ vals,
        int* __restrict__ bucket_cnt,
        int2* __restrict__ packed,
        int* __restrict__ ovf_cnt,
        int* __restrict__ ovf_list,
        int E, int nb, int cap, int chunk) {
    __shared__ int hist[MAXB];
    int tid = threadIdx.x;
    int start = blockIdx.x * chunk;
    int end = start + chunk; if (end > E) end = E;

    for (int i = tid; i < nb; i += 1024) hist[i] = 0;
    __syncthreads();

    int rr[EPT1]; int cc[EPT1]; float vv[EPT1];
    int ne = 0;
    for (int e = start + tid; e < end; e += 1024) {
        int r = rows[e];
        if (ne < EPT1) { rr[ne] = r; cc[ne] = cols[e]; vv[ne] = vals[e]; }
        ++ne;
        atomicAdd(&hist[r >> RPB_SHIFT], 1);
    }
    __syncthreads();

    for (int bkt = tid; bkt < nb; bkt += 1024) {
        int c = hist[bkt];
        hist[bkt] = (c > 0) ? atomicAdd(&bucket_cnt[bkt], c) : 0;
    }
    __syncthreads();

    int j = 0;
    for (int e = start + tid; e < end; e += 1024, ++j) {
        int r, c; float v;
        if (j < EPT1) { r = rr[j]; c = cc[j]; v = vv[j]; }
        else          { r = rows[e]; c = cols[e]; v = vals[e]; }
        int bkt = r >> RPB_SHIFT;
        int local = atomicAdd(&hist[bkt], 1);
        if (local < cap) {
            int key = ((r & (RPB - 1)) << 17) | c;
            packed[(size_t)bkt * cap + local] = make_int2(key, __float_as_int(v));
        } else {
            int k = atomicAdd(ovf_cnt, 1);
            if (k < OVF_MAX) ovf_list[k] = e;
        }
    }
}

template <bool HALF>
__global__ __launch_bounds__(256) void phase2_sort_gather(
        const int* __restrict__ bucket_cnt,
        const int2* __restrict__ packed,
        const __half* __restrict__ bh,
        const float* __restrict__ b,
        float* __restrict__ out,
        int cap, int N) {
    __shared__ int2 sorted[CAP_LDS];
    __shared__ int hist[RPB];
    __shared__ int offs[RPB + 1];
    __shared__ int cursor[RPB];

    int bucket = blockIdx.x;
    int tid = threadIdx.x;

    int cnt = bucket_cnt[bucket];
    if (cnt > cap) cnt = cap;
    const int2* pk = packed + (size_t)bucket * cap;

    if (tid < RPB) hist[tid] = 0;
    __syncthreads();

    int2 ev[EPT];
    int  rl[EPT];
    int ne = 0;
    for (int i = tid; i < cnt; i += 256) {
        int2 e = pk[i];
        ev[ne] = e;
        rl[ne] = ((unsigned)e.x) >> 17;
        atomicAdd(&hist[rl[ne]], 1);
        ++ne;
    }
    __syncthreads();

    for (int d = 1; d < RPB; d <<= 1) {
        int t = (tid < RPB && tid >= d) ? hist[tid - d] : 0;
        __syncthreads();
        if (tid < RPB) hist[tid] += t;
        __syncthreads();
    }
    if (tid == 0) offs[0] = 0;
    if (tid < RPB) {
        offs[tid + 1] = hist[tid];
        cursor[tid] = (tid == 0) ? 0 : hist[tid - 1];
    }
    __syncthreads();

    for (int j = 0; j < ne; ++j) {
        int pos = atomicAdd(&cursor[rl[j]], 1);
        sorted[pos] = make_int2(ev[j].x & 0x1FFFF, ev[j].y);
    }
    __syncthreads();

    int g = tid >> 5;
    int glane = tid & 31;
    int r0 = bucket << RPB_SHIFT;
    for (int k = 0; k < 8; ++k) {
        int rr = g * 8 + k;
        int start = offs[rr];
        int num = offs[rr + 1] - start;
        float4 acc = make_float4(0.f, 0.f, 0.f, 0.f);
        for (int base = 0; base < num; base += 8) {
#pragma unroll
            for (int j = 0; j < 8; ++j) {
                int idx = base + j;
                int sidx = start + ((idx < num) ? idx : (num - 1));
                int2 e = sorted[sidx];
                float v = (idx < num) ? __int_as_float(e.y) : 0.f;
                if (HALF) {
                    uint2 hv = ((const uint2*)(bh + (size_t)e.x * D_DIM))[glane];
                    __half2* hp = (__half2*)&hv;
                    float2 f0 = __half22float2(hp[0]);
                    float2 f1 = __half22float2(hp[1]);
                    acc.x += v * f0.x;
                    acc.y += v * f0.y;
                    acc.z += v * f1.x;
                    acc.w += v * f1.y;
                } else {
                    float4 bv = ((const float4*)(b + (size_t)e.x * D_DIM))[glane];
                    acc.x += v * bv.x;
                    acc.y += v * bv.y;
                    acc.z += v * bv.z;
                    acc.w += v * bv.w;
                }
            }
        }
        int r = r0 + rr;
        if (r < N) {
            fx4 av = {acc.x, acc.y, acc.z, acc.w};
            __builtin_nontemporal_store(av, (fx4*)(out + (size_t)r * D_DIM) + glane);
        }
    }
}

// ---------------- overflow fixup (normally ~0 items; runs AFTER phase2) -----
__global__ void fixup_kernel(const int* __restrict__ ovf_cnt,
                             const int* __restrict__ ovf_list,
                             const int* __restrict__ rows,
                             const int* __restrict__ cols,
                             const float* __restrict__ vals,
                             const float* __restrict__ b,
                             float* __restrict__ out) {
    int items = *ovf_cnt;
    if (items > OVF_MAX) items = OVF_MAX;
    int gsz  = (gridDim.x * blockDim.x) >> 5;
    int gid  = (blockIdx.x * blockDim.x + threadIdx.x) >> 5;
    int lane = threadIdx.x & 31;
    for (int i = gid; i < items; i += gsz) {
        int e = ovf_list[i];
        int r = rows[e];
        int c = cols[e];
        float v = vals[e];
        float4 bv = ((const float4*)(b + (size_t)c * D_DIM))[lane];
        float* op = out + (size_t)r * D_DIM + (size_t)lane * 4;
        atomicAdd(op + 0, v * bv.x);
        atomicAdd(op + 1, v * bv.y);
        atomicAdd(op + 2, v * bv.z);
        atomicAdd(op + 3, v * bv.w);
    }
}

// ---------------- fallback (v1 atomic) ----------------
__global__ void spmm_atomic_kernel(const int* __restrict__ rows,
                                   const int* __restrict__ cols,
                                   const float* __restrict__ vals,
                                   const float* __restrict__ b,
                                   float* __restrict__ out, int E) {
    int t = blockIdx.x * blockDim.x + threadIdx.x;
    int e = t >> 5;
    if (e >= E) return;
    int lane = t & 31;
    int r = rows[e];
    int c = cols[e];
    float v = vals[e];
    float4 bv = ((const float4*)(b + (size_t)c * D_DIM))[lane];
    float* op = out + (size_t)r * D_DIM + (size_t)lane * 4;
    atomicAdd(op + 0, v * bv.x);
    atomicAdd(op + 1, v * bv.y);
    atomicAdd(op + 2, v * bv.z);
    atomicAdd(op + 3, v * bv.w);
}

extern "C" void kernel_launch(void* const* d_in, const int* in_sizes, int n_in,
                              void* d_out, int out_size, void* d_ws, size_t ws_size,
                              hipStream_t stream) {
    const int*   indices = (const int*)d_in[0];
    const float* vals    = (const float*)d_in[1];
    const float* b       = (const float*)d_in[3];
    float*       out     = (float*)d_out;

    int E = in_sizes[1];
    int N = out_size / D_DIM;
    const int* rows = indices;
    const int* cols = indices + E;

    size_t bh_bytes = (size_t)N * D_DIM * 2;
    int n8 = N * D_DIM / 8;

    // ---- try row-direct layout: row_cnt[N] | ovf | ovf_list | bh | packed ----
    {
        size_t fixedR = (size_t)N * 4 + 4 + (size_t)OVF_MAX * 4;
        size_t bh_off = (fixedR + 255) & ~(size_t)255;
        size_t pk_off = (bh_off + bh_bytes + 255) & ~(size_t)255;
        size_t avail  = (ws_size > pk_off) ? (ws_size - pk_off) : 0;
        size_t capr_s = avail / ((size_t)N * 8);
        int capr = (capr_s > CAPR_MAX) ? CAPR_MAX : (int)capr_s;
        if (capr >= CAPR_MIN) {
            char* w = (char*)d_ws;
            int*    row_cnt  = (int*)w;
            int*    ovf_cnt  = (int*)(w + (size_t)N * 4);
            int*    ovf_list = (int*)(w + (size_t)N * 4 + 4);
            __half* bh       = (__half*)(w + bh_off);
            int2*   packed   = (int2*)(w + pk_off);

            (void)hipMemsetAsync(row_cnt, 0, (size_t)N * 4 + 4, stream);

            convert_b_kernel<<<(n8 + 255) / 256, 256, 0, stream>>>(b, bh, n8);

            int p1b = 2048;
            phase1_rows<<<p1b, 256, 0, stream>>>(
                rows, cols, vals, row_cnt, packed, ovf_cnt, ovf_list, E, capr);

            int p2b = (N + 7) / 8;
            phase2_rows<true><<<p2b, 256, 0, stream>>>(
                row_cnt, packed, bh, (const float*)nullptr, out, capr, N);

            fixup_kernel<<<8, 256, 0, stream>>>(
                ovf_cnt, ovf_list, rows, cols, vals, b, out);
            return;
        }
    }

    // ---- v7 bucket-sort fallback ----
    int nb = (N + RPB - 1) >> RPB_SHIFT;     // 1563 for N=100000
    int avg = (nb > 0) ? E / nb : 0;         // ~1023
    int cap = CAP_LDS;

    size_t fixed      = (size_t)nb * 4 + 4 + (size_t)OVF_MAX * 4;
    size_t bh_off     = (fixed + 255) & ~(size_t)255;
    size_t packed_h   = (bh_off + bh_bytes + 255) & ~(size_t)255;  // fp16 layout
    size_t packed_f   = bh_off;                                    // fp32 layout
    size_t need_h     = packed_h + (size_t)nb * cap * 8;
    size_t need_f     = packed_f + (size_t)nb * cap * 8;

    bool okBase = (nb <= MAXB) && (N <= 131072) && (cap > avg + avg / 8);
    bool useHalf = okBase && (ws_size >= need_h);
    bool useF32  = okBase && !useHalf && (ws_size >= need_f);

    if (!useHalf && !useF32) {
        (void)hipMemsetAsync(d_out, 0, (size_t)out_size * sizeof(float), stream);
        long long total = (long long)E * 32;
        int blocks = (int)((total + 255) / 256);
        spmm_atomic_kernel<<<blocks, 256, 0, stream>>>(rows, cols, vals, b, out, E);
        return;
    }

    char* w = (char*)d_ws;
    int*    bucket_cnt = (int*)w;
    int*    ovf_cnt    = (int*)(w + (size_t)nb * 4);
    int*    ovf_list   = (int*)(w + (size_t)nb * 4 + 4);
    __half* bh         = (__half*)(w + bh_off);
    int2*   packed     = (int2*)(w + (useHalf ? packed_h : packed_f));

    (void)hipMemsetAsync(bucket_cnt, 0, (size_t)nb * 4 + 4, stream);

    if (useHalf)
        convert_b_kernel<<<(n8 + 255) / 256, 256, 0, stream>>>(b, bh, n8);

    const int P1_WGS = 256;
    int chunk = (E + P1_WGS - 1) / P1_WGS;
    phase1_partition<<<P1_WGS, 1024, 0, stream>>>(
        rows, cols, vals, bucket_cnt, packed, ovf_cnt, ovf_list, E, nb, cap, chunk);

    if (useHalf)
        phase2_sort_gather<true><<<nb, 256, 0, stream>>>(
            bucket_cnt, packed, bh, b, out, cap, N);
    else
        phase2_sort_gather<false><<<nb, 256, 0, stream>>>(
            bucket_cnt, packed, bh, b, out, cap, N);

    fixup_kernel<<<8, 256, 0, stream>>>(ovf_cnt, ovf_list, rows, cols, vals, b, out);
}

// Round 5
// 228.219 us; speedup vs baseline: 1.2924x; 1.2924x over previous
//
#include <hip/hip_runtime.h>
#include <hip/hip_fp16.h>

// COO SpMM: out[row[e], :] += values[e] * b[col[e], :]
// N=100000, E=1600000, D=128, fp32.
// v11: two-level radix partition replaces the single-shot scatter.
//   Evidence: v7 phase1 (bucket scatter) and v10 phase1 (row scatter) BOTH
//   ~106us with 4x/8x write amplification (51MB/99.5MB for 12.8MB logical):
//   partial-line 8B scatter writebacks are the wall, not atomics or reads.
//   - p1_coarse: 391 bins of 256 rows; per-(WG,bin) runs ~16 edges (128B);
//     open-line footprint 32WGx391 ~ 800KB/XCD < 4MB L2 -> full-line wb.
//   - p2_fine: 1 WG per coarse bin; LDS counting-sort (36.9KB stage) into its
//     4 fine 64-row buckets; coalesced run writes; exact bucket_cnt, 0 atomics.
//   - phase2_sort_gather / convert_b: v7 verbatim (proven 72.7us / 13us).
//   - overflow now (r,c,v) triples shared by all paths; coarse region unions
//     with bh (convert runs after p2_fine) -> ws ~43.4MB, same as v7.

#define D_DIM 128
#define RPB 64            // rows per fine bucket (phase2)
#define RPB_SHIFT 6
#define CRB 256           // rows per coarse bin (= 4 fine buckets)
#define CRB_SHIFT 8
#define MAXCB 512         // coarse-bin LDS histogram capacity (N <= 131072)
#define CCAP 4608         // coarse bin capacity (avg ~4092 @ E=1.6M, N=100K)
#define MAXB 2048         // v7 fallback phase1 LDS histogram capacity
#define CAP_LDS 1408      // max edges per fine bucket in phase2 LDS
#define EPT 6             // phase2: ceil(CAP_LDS/256) edges/thread in regs
#define EPT1 8            // p1: cached edges/thread (chunk <= 8192)
#define OVF_T 8192        // overflow triples (r,c,vbits)

typedef float fx4 __attribute__((ext_vector_type(4)));

// ---------------- b -> fp16 conversion (row-major) ----------------
__global__ __launch_bounds__(256) void convert_b_kernel(
        const float* __restrict__ b, __half* __restrict__ bh, int n8) {
    int i = blockIdx.x * blockDim.x + threadIdx.x;
    if (i >= n8) return;
    const float4* b4 = (const float4*)b;
    float4 a0 = b4[2 * i];
    float4 a1 = b4[2 * i + 1];
    union { __half2 h[4]; uint4 u; } pk;
    pk.h[0] = __floats2half2_rn(a0.x, a0.y);
    pk.h[1] = __floats2half2_rn(a0.z, a0.w);
    pk.h[2] = __floats2half2_rn(a1.x, a1.y);
    pk.h[3] = __floats2half2_rn(a1.z, a1.w);
    ((uint4*)bh)[i] = pk.u;
}

// ---------------- pass 1: edges -> coarse bins (256 rows each) -------------
// coarse element: .x = ((r & 255) << 17) | c   (c < 131072), .y = val bits
__global__ __launch_bounds__(1024) void p1_coarse(
        const int* __restrict__ rows,
        const int* __restrict__ cols,
        const float* __restrict__ vals,
        int* __restrict__ coarse_cnt,
        int2* __restrict__ coarse,
        int* __restrict__ ovf_cnt,
        int* __restrict__ ovf3,
        int E, int ncb, int ccap, int chunk) {
    __shared__ int hist[MAXCB];
    int tid = threadIdx.x;
    int start = blockIdx.x * chunk;
    int end = start + chunk; if (end > E) end = E;

    for (int i = tid; i < ncb; i += 1024) hist[i] = 0;
    __syncthreads();

    // pass A: local histogram; cache edges in registers
    int rr[EPT1]; int cc[EPT1]; float vv[EPT1];
    int ne = 0;
    for (int e = start + tid; e < end; e += 1024) {
        int r = rows[e];
        if (ne < EPT1) { rr[ne] = r; cc[ne] = cols[e]; vv[ne] = vals[e]; }
        ++ne;
        atomicAdd(&hist[r >> CRB_SHIFT], 1);
    }
    __syncthreads();

    // bulk reservation: one global atomic per (WG, nonempty bin)
    for (int bin = tid; bin < ncb; bin += 1024) {
        int c = hist[bin];
        hist[bin] = (c > 0) ? atomicAdd(&coarse_cnt[bin], c) : 0;
    }
    __syncthreads();

    // pass B: place edges; per-(WG,bin) writes are cursor-contiguous runs
    int j = 0;
    for (int e = start + tid; e < end; e += 1024, ++j) {
        int r, c; float v;
        if (j < EPT1) { r = rr[j]; c = cc[j]; v = vv[j]; }
        else          { r = rows[e]; c = cols[e]; v = vals[e]; }
        int bin = r >> CRB_SHIFT;
        int local = atomicAdd(&hist[bin], 1);
        if (local < ccap) {
            coarse[(size_t)bin * ccap + local] =
                make_int2(((r & (CRB - 1)) << 17) | c, __float_as_int(v));
        } else {
            int k = atomicAdd(ovf_cnt, 1);
            if (k < OVF_T) {
                ovf3[3 * k] = r; ovf3[3 * k + 1] = c;
                ovf3[3 * k + 2] = __float_as_int(v);
            }
        }
    }
}

// ---------------- pass 2: coarse bin -> 4 fine buckets (LDS counting sort) --
__global__ __launch_bounds__(1024) void p2_fine(
        const int* __restrict__ coarse_cnt,
        const int2* __restrict__ coarse,
        int* __restrict__ bucket_cnt,
        int2* __restrict__ packed,
        int* __restrict__ ovf_cnt,
        int* __restrict__ ovf3,
        int ccap, int cap, int nb) {
    __shared__ int2 stage[CCAP];
    __shared__ int hist4[4];
    __shared__ int loff[5];
    __shared__ int cur[4];

    int bin = blockIdx.x;
    int tid = threadIdx.x;
    int lane = tid & 63;
    int cnt = coarse_cnt[bin];
    if (cnt > ccap) cnt = ccap;
    const int2* cb = coarse + (size_t)bin * ccap;

    if (tid < 4) hist4[tid] = 0;

    // per-thread histogram of the 4 fine bins (fine = bits 23..24 of .x)
    int h0 = 0, h1 = 0, h2 = 0, h3 = 0;
    for (int i = tid; i < cnt; i += 1024) {
        int f = (cb[i].x >> 23) & 3;
        h0 += (f == 0); h1 += (f == 1); h2 += (f == 2); h3 += (f == 3);
    }
    // wave reduce, then 1 LDS atomic per wave per bin
    for (int off = 32; off; off >>= 1) {
        h0 += __shfl_down(h0, off); h1 += __shfl_down(h1, off);
        h2 += __shfl_down(h2, off); h3 += __shfl_down(h3, off);
    }
    __syncthreads();          // hist4 init visible
    if (lane == 0) {
        atomicAdd(&hist4[0], h0); atomicAdd(&hist4[1], h1);
        atomicAdd(&hist4[2], h2); atomicAdd(&hist4[3], h3);
    }
    __syncthreads();
    if (tid == 0) {
        int o = 0;
        for (int k = 0; k < 4; ++k) { loff[k] = o; cur[k] = o; o += hist4[k]; }
        loff[4] = o;
    }
    __syncthreads();

    // scatter into row-sorted LDS stage; ballot-aggregated cursor atomics
    for (int i = tid; i < cnt; i += 1024) {
        int2 e = cb[i];
        int f = (e.x >> 23) & 3;
        int p = 0;
        for (int k = 0; k < 4; ++k) {
            unsigned long long m = __ballot(f == k);
            if (f == k) {
                int leader = __ffsll((unsigned long long)m) - 1;
                int base = 0;
                if (lane == leader) base = atomicAdd(&cur[k], (int)__popcll(m));
                base = __shfl(base, leader);
                p = base + (int)__popcll(m & ((1ULL << lane) - 1ULL));
            }
        }
        stage[p] = e;
    }
    __syncthreads();

    // flush runs -> packed (coalesced), exact bucket_cnt, no atomics
    int fb0 = bin << (CRB_SHIFT - RPB_SHIFT);   // first fine bucket (x4)
    for (int k = 0; k < 4; ++k) {
        int bkt = fb0 + k;
        if (bkt >= nb) break;
        int s = loff[k];
        int run = loff[k + 1] - s;
        int w = (run > cap) ? cap : run;
        for (int i = tid; i < w; i += 1024) {
            int2 e = stage[s + i];
            // coarse key ((r&255)<<17|c) -> phase2 key ((r&63)<<17|c)
            packed[(size_t)bkt * cap + i] = make_int2(e.x & 0x7FFFFF, e.y);
        }
        if (tid == 0) bucket_cnt[bkt] = w;
        for (int i = cap + tid; i < run; i += 1024) {
            int2 e = stage[s + i];
            int k2 = atomicAdd(ovf_cnt, 1);
            if (k2 < OVF_T) {
                int r = (bin << CRB_SHIFT) | ((unsigned)e.x >> 17);
                ovf3[3 * k2] = r; ovf3[3 * k2 + 1] = e.x & 0x1FFFF;
                ovf3[3 * k2 + 2] = e.y;
            }
        }
    }
}

// ---------------- phase 2: sort bucket by row, register-accumulate (v7) -----
template <bool HALF>
__global__ __launch_bounds__(256) void phase2_sort_gather(
        const int* __restrict__ bucket_cnt,
        const int2* __restrict__ packed,
        const __half* __restrict__ bh,
        const float* __restrict__ b,
        float* __restrict__ out,
        int cap, int N) {
    __shared__ int2 sorted[CAP_LDS];
    __shared__ int hist[RPB];
    __shared__ int offs[RPB + 1];
    __shared__ int cursor[RPB];

    int bucket = blockIdx.x;
    int tid = threadIdx.x;

    int cnt = bucket_cnt[bucket];
    if (cnt > cap) cnt = cap;
    const int2* pk = packed + (size_t)bucket * cap;

    if (tid < RPB) hist[tid] = 0;
    __syncthreads();

    int2 ev[EPT];
    int  rl[EPT];
    int ne = 0;
    for (int i = tid; i < cnt; i += 256) {
        int2 e = pk[i];
        ev[ne] = e;
        rl[ne] = ((unsigned)e.x) >> 17;
        atomicAdd(&hist[rl[ne]], 1);
        ++ne;
    }
    __syncthreads();

    for (int d = 1; d < RPB; d <<= 1) {
        int t = (tid < RPB && tid >= d) ? hist[tid - d] : 0;
        __syncthreads();
        if (tid < RPB) hist[tid] += t;
        __syncthreads();
    }
    if (tid == 0) offs[0] = 0;
    if (tid < RPB) {
        offs[tid + 1] = hist[tid];
        cursor[tid] = (tid == 0) ? 0 : hist[tid - 1];
    }
    __syncthreads();

    for (int j = 0; j < ne; ++j) {
        int pos = atomicAdd(&cursor[rl[j]], 1);
        sorted[pos] = make_int2(ev[j].x & 0x1FFFF, ev[j].y);
    }
    __syncthreads();

    int g = tid >> 5;
    int glane = tid & 31;
    int r0 = bucket << RPB_SHIFT;
    for (int k = 0; k < 8; ++k) {
        int rr = g * 8 + k;
        int start = offs[rr];
        int num = offs[rr + 1] - start;
        float4 acc = make_float4(0.f, 0.f, 0.f, 0.f);
        for (int base = 0; base < num; base += 8) {
#pragma unroll
            for (int j = 0; j < 8; ++j) {
                int idx = base + j;
                int sidx = start + ((idx < num) ? idx : (num - 1));
                int2 e = sorted[sidx];
                float v = (idx < num) ? __int_as_float(e.y) : 0.f;
                if (HALF) {
                    uint2 hv = ((const uint2*)(bh + (size_t)e.x * D_DIM))[glane];
                    __half2* hp = (__half2*)&hv;
                    float2 f0 = __half22float2(hp[0]);
                    float2 f1 = __half22float2(hp[1]);
                    acc.x += v * f0.x;
                    acc.y += v * f0.y;
                    acc.z += v * f1.x;
                    acc.w += v * f1.y;
                } else {
                    float4 bv = ((const float4*)(b + (size_t)e.x * D_DIM))[glane];
                    acc.x += v * bv.x;
                    acc.y += v * bv.y;
                    acc.z += v * bv.z;
                    acc.w += v * bv.w;
                }
            }
        }
        int r = r0 + rr;
        if (r < N) {
            fx4 av = {acc.x, acc.y, acc.z, acc.w};
            __builtin_nontemporal_store(av, (fx4*)(out + (size_t)r * D_DIM) + glane);
        }
    }
}

// ---------------- v7 fallback phase1 (triples spill) ------------------------
__global__ __launch_bounds__(1024) void phase1_partition(
        const int* __restrict__ rows,
        const int* __restrict__ cols,
        const float* __restrict__ vals,
        int* __restrict__ bucket_cnt,
        int2* __restrict__ packed,
        int* __restrict__ ovf_cnt,
        int* __restrict__ ovf3,
        int E, int nb, int cap, int chunk) {
    __shared__ int hist[MAXB];
    int tid = threadIdx.x;
    int start = blockIdx.x * chunk;
    int end = start + chunk; if (end > E) end = E;

    for (int i = tid; i < nb; i += 1024) hist[i] = 0;
    __syncthreads();

    int rr[EPT1]; int cc[EPT1]; float vv[EPT1];
    int ne = 0;
    for (int e = start + tid; e < end; e += 1024) {
        int r = rows[e];
        if (ne < EPT1) { rr[ne] = r; cc[ne] = cols[e]; vv[ne] = vals[e]; }
        ++ne;
        atomicAdd(&hist[r >> RPB_SHIFT], 1);
    }
    __syncthreads();

    for (int bkt = tid; bkt < nb; bkt += 1024) {
        int c = hist[bkt];
        hist[bkt] = (c > 0) ? atomicAdd(&bucket_cnt[bkt], c) : 0;
    }
    __syncthreads();

    int j = 0;
    for (int e = start + tid; e < end; e += 1024, ++j) {
        int r, c; float v;
        if (j < EPT1) { r = rr[j]; c = cc[j]; v = vv[j]; }
        else          { r = rows[e]; c = cols[e]; v = vals[e]; }
        int bkt = r >> RPB_SHIFT;
        int local = atomicAdd(&hist[bkt], 1);
        if (local < cap) {
            int key = ((r & (RPB - 1)) << 17) | c;
            packed[(size_t)bkt * cap + local] = make_int2(key, __float_as_int(v));
        } else {
            int k = atomicAdd(ovf_cnt, 1);
            if (k < OVF_T) {
                ovf3[3 * k] = r; ovf3[3 * k + 1] = c;
                ovf3[3 * k + 2] = __float_as_int(v);
            }
        }
    }
}

// ---------------- overflow fixup: (r,c,v) triples ---------------------------
__global__ void fixup_kernel(const int* __restrict__ ovf_cnt,
                             const int* __restrict__ ovf3,
                             const float* __restrict__ b,
                             float* __restrict__ out) {
    int items = *ovf_cnt;
    if (items > OVF_T) items = OVF_T;
    int gsz  = (gridDim.x * blockDim.x) >> 5;
    int gid  = (blockIdx.x * blockDim.x + threadIdx.x) >> 5;
    int lane = threadIdx.x & 31;
    for (int i = gid; i < items; i += gsz) {
        int r = ovf3[3 * i];
        int c = ovf3[3 * i + 1];
        float v = __int_as_float(ovf3[3 * i + 2]);
        float4 bv = ((const float4*)(b + (size_t)c * D_DIM))[lane];
        float* op = out + (size_t)r * D_DIM + (size_t)lane * 4;
        atomicAdd(op + 0, v * bv.x);
        atomicAdd(op + 1, v * bv.y);
        atomicAdd(op + 2, v * bv.z);
        atomicAdd(op + 3, v * bv.w);
    }
}

// ---------------- fallback (v1 atomic) ----------------
__global__ void spmm_atomic_kernel(const int* __restrict__ rows,
                                   const int* __restrict__ cols,
                                   const float* __restrict__ vals,
                                   const float* __restrict__ b,
                                   float* __restrict__ out, int E) {
    int t = blockIdx.x * blockDim.x + threadIdx.x;
    int e = t >> 5;
    if (e >= E) return;
    int lane = t & 31;
    int r = rows[e];
    int c = cols[e];
    float v = vals[e];
    float4 bv = ((const float4*)(b + (size_t)c * D_DIM))[lane];
    float* op = out + (size_t)r * D_DIM + (size_t)lane * 4;
    atomicAdd(op + 0, v * bv.x);
    atomicAdd(op + 1, v * bv.y);
    atomicAdd(op + 2, v * bv.z);
    atomicAdd(op + 3, v * bv.w);
}

extern "C" void kernel_launch(void* const* d_in, const int* in_sizes, int n_in,
                              void* d_out, int out_size, void* d_ws, size_t ws_size,
                              hipStream_t stream) {
    const int*   indices = (const int*)d_in[0];
    const float* vals    = (const float*)d_in[1];
    const float* b       = (const float*)d_in[3];
    float*       out     = (float*)d_out;

    int E = in_sizes[1];
    int N = out_size / D_DIM;
    const int* rows = indices;
    const int* cols = indices + E;

    int nb  = (N + RPB - 1) >> RPB_SHIFT;     // 1563
    int ncb = (N + CRB - 1) >> CRB_SHIFT;     // 391
    int avg  = (nb  > 0) ? E / nb  : 0;       // ~1023
    int cavg = (ncb > 0) ? E / ncb : 0;       // ~4092
    int cap = CAP_LDS;
    size_t bh_bytes = (size_t)N * D_DIM * 2;
    int n8 = N * D_DIM / 8;

    // ---- new radix path ----
    {
        bool ok = (ncb <= MAXCB) && (N <= 131072) &&
                  (cavg + cavg / 8 <= CCAP) && (cap > avg + avg / 8);
        size_t fixedN = (size_t)ncb * 4 + (size_t)nb * 4 + 4 + (size_t)OVF_T * 12;
        size_t pk_off = (fixedN + 255) & ~(size_t)255;
        size_t un_off = (pk_off + (size_t)nb * cap * 8 + 255) & ~(size_t)255;
        size_t coarse_bytes = (size_t)ncb * CCAP * 8;
        size_t un_bytes = coarse_bytes > bh_bytes ? coarse_bytes : bh_bytes;
        if (ok && ws_size >= un_off + un_bytes) {
            char* w = (char*)d_ws;
            int*    coarse_cnt = (int*)w;
            int*    bucket_cnt = (int*)(w + (size_t)ncb * 4);
            int*    ovf_cnt    = (int*)(w + (size_t)ncb * 4 + (size_t)nb * 4);
            int*    ovf3       = (int*)(w + (size_t)ncb * 4 + (size_t)nb * 4 + 4);
            int2*   packed     = (int2*)(w + pk_off);
            int2*   coarse     = (int2*)(w + un_off);
            __half* bh         = (__half*)(w + un_off);

            (void)hipMemsetAsync(coarse_cnt, 0,
                                 (size_t)ncb * 4 + (size_t)nb * 4 + 4, stream);

            const int P1_WGS = 256;
            int chunk = (E + P1_WGS - 1) / P1_WGS;
            p1_coarse<<<P1_WGS, 1024, 0, stream>>>(
                rows, cols, vals, coarse_cnt, coarse, ovf_cnt, ovf3,
                E, ncb, CCAP, chunk);

            p2_fine<<<ncb, 1024, 0, stream>>>(
                coarse_cnt, coarse, bucket_cnt, packed, ovf_cnt, ovf3,
                CCAP, cap, nb);

            // bh overwrites coarse region (dead after p2_fine)
            convert_b_kernel<<<(n8 + 255) / 256, 256, 0, stream>>>(b, bh, n8);

            phase2_sort_gather<true><<<nb, 256, 0, stream>>>(
                bucket_cnt, packed, bh, b, out, cap, N);

            fixup_kernel<<<8, 256, 0, stream>>>(ovf_cnt, ovf3, b, out);
            return;
        }
    }

    // ---- v7 bucket-sort fallback ----
    size_t fixed      = (size_t)nb * 4 + 4 + (size_t)OVF_T * 12;
    size_t bh_off     = (fixed + 255) & ~(size_t)255;
    size_t packed_h   = (bh_off + bh_bytes + 255) & ~(size_t)255;  // fp16 layout
    size_t packed_f   = bh_off;                                    // fp32 layout
    size_t need_h     = packed_h + (size_t)nb * cap * 8;
    size_t need_f     = packed_f + (size_t)nb * cap * 8;

    bool okBase = (nb <= MAXB) && (N <= 131072) && (cap > avg + avg / 8);
    bool useHalf = okBase && (ws_size >= need_h);
    bool useF32  = okBase && !useHalf && (ws_size >= need_f);

    if (!useHalf && !useF32) {
        (void)hipMemsetAsync(d_out, 0, (size_t)out_size * sizeof(float), stream);
        long long total = (long long)E * 32;
        int blocks = (int)((total + 255) / 256);
        spmm_atomic_kernel<<<blocks, 256, 0, stream>>>(rows, cols, vals, b, out, E);
        return;
    }

    char* w = (char*)d_ws;
    int*    bucket_cnt = (int*)w;
    int*    ovf_cnt    = (int*)(w + (size_t)nb * 4);
    int*    ovf3       = (int*)(w + (size_t)nb * 4 + 4);
    __half* bh         = (__half*)(w + bh_off);
    int2*   packed     = (int2*)(w + (useHalf ? packed_h : packed_f));

    (void)hipMemsetAsync(bucket_cnt, 0, (size_t)nb * 4 + 4, stream);

    if (useHalf)
        convert_b_kernel<<<(n8 + 255) / 256, 256, 0, stream>>>(b, bh, n8);

    const int P1_WGS = 256;
    int chunk = (E + P1_WGS - 1) / P1_WGS;
    phase1_partition<<<P1_WGS, 1024, 0, stream>>>(
        rows, cols, vals, bucket_cnt, packed, ovf_cnt, ovf3, E, nb, cap, chunk);

    if (useHalf)
        phase2_sort_gather<true><<<nb, 256, 0, stream>>>(
            bucket_cnt, packed, bh, b, out, cap, N);
    else
        phase2_sort_gather<false><<<nb, 256, 0, stream>>>(
            bucket_cnt, packed, bh, b, out, cap, N);

    fixup_kernel<<<8, 256, 0, stream>>>(ovf_cnt, ovf3, b, out);
}

// Round 6
// 216.890 us; speedup vs baseline: 1.3599x; 1.0522x over previous
//
#include <hip/hip_runtime.h>
#include <hip/hip_fp16.h>

// COO SpMM: out[row[e], :] += values[e] * b[col[e], :]
// N=100000, E=1600000, D=128, fp32.
// v12: phase1 = LOCAL LDS COUNTING SORT + coalesced run writes.
//   Evidence chain: v7/v10/v11 phase1 all ~60-106us regardless of structure;
//   v11 cut write BYTES (51->40MB) with zero time change -> the wall is store
//   TRANSACTIONS (per-lane 8B stores to ~55-64 distinct cursors per wave),
//   not writeback volume. p2_fine (coalesced r/w of same 12.8MB) ~14us proves
//   the bytes are cheap when contiguous.
//   - p1_sortcoarse: chunk=4096 edges/WG in regs; 391-bin LDS hist; 9-step
//     H-S scan; scatter into bin-sorted LDS stage (44KB); bulk global
//     reservation (1 atomic/WG/bin); LINEAR flush: lane i writes stage[i] to
//     gres[bkt]+(i-excl[bkt]) -> runs of ~10 edges -> ~6-8 store txn/wave.
//   - p2_fine, convert_b, phase2_sort_gather, fixup: v11 verbatim.

#define D_DIM 128
#define RPB 64            // rows per fine bucket (phase2)
#define RPB_SHIFT 6
#define CRB 256           // rows per coarse bin (= 4 fine buckets)
#define CRB_SHIFT 8
#define MAXCB 512         // coarse-bin count capacity (N <= 131072)
#define CCAP 4608         // coarse bin capacity (avg ~4092 @ E=1.6M, N=100K)
#define MAXB 2048         // v7 fallback phase1 LDS histogram capacity
#define CAP_LDS 1408      // max edges per fine bucket in phase2 LDS
#define EPT 6             // phase2: ceil(CAP_LDS/256) edges/thread in regs
#define EPT1 8            // v7 fallback p1: cached edges/thread
#define CHUNK1 4096       // p1_sortcoarse: edges per WG (= 4/thread)
#define EPC 4             // p1_sortcoarse: cached edges/thread
#define OVF_T 8192        // overflow triples (r,c,vbits)

typedef float fx4 __attribute__((ext_vector_type(4)));

// ---------------- b -> fp16 conversion (row-major) ----------------
__global__ __launch_bounds__(256) void convert_b_kernel(
        const float* __restrict__ b, __half* __restrict__ bh, int n8) {
    int i = blockIdx.x * blockDim.x + threadIdx.x;
    if (i >= n8) return;
    const float4* b4 = (const float4*)b;
    float4 a0 = b4[2 * i];
    float4 a1 = b4[2 * i + 1];
    union { __half2 h[4]; uint4 u; } pk;
    pk.h[0] = __floats2half2_rn(a0.x, a0.y);
    pk.h[1] = __floats2half2_rn(a0.z, a0.w);
    pk.h[2] = __floats2half2_rn(a1.x, a1.y);
    pk.h[3] = __floats2half2_rn(a1.z, a1.w);
    ((uint4*)bh)[i] = pk.u;
}

// ---------------- pass 1: local sort by coarse bin, coalesced flush ---------
// coarse element: .x = ((r & 255) << 17) | c   (c < 131072), .y = val bits
__global__ __launch_bounds__(1024) void p1_sortcoarse(
        const int* __restrict__ rows,
        const int* __restrict__ cols,
        const float* __restrict__ vals,
        int* __restrict__ coarse_cnt,
        int2* __restrict__ coarse,
        int* __restrict__ ovf_cnt,
        int* __restrict__ ovf3,
        int E, int ncb, int ccap) {
    __shared__ int hist[MAXCB];            // counts -> incl scan -> gofs
    __shared__ int cursor[MAXCB];          // scatter cursors (excl offsets)
    __shared__ int2 stage[CHUNK1];         // bin-sorted edges
    __shared__ unsigned short sbkt[CHUNK1];// bin id per stage slot

    int tid = threadIdx.x;
    int start = blockIdx.x * CHUNK1;
    int end = start + CHUNK1; if (end > E) end = E;
    int n = end - start;

    for (int i = tid; i < ncb; i += 1024) hist[i] = 0;
    __syncthreads();

    // load edges into registers + histogram
    int rr[EPC]; int cc[EPC]; float vv[EPC];
    int ne = 0;
    for (int e = start + tid; e < end; e += 1024) {
        int r = rows[e];
        if (ne < EPC) { rr[ne] = r; cc[ne] = cols[e]; vv[ne] = vals[e]; }
        ++ne;
        atomicAdd(&hist[r >> CRB_SHIFT], 1);
    }
    __syncthreads();

    // inclusive Hillis-Steele scan over ncb bins (ncb <= 1024: 1 elem/thread)
    for (int d = 1; d < ncb; d <<= 1) {
        int t = (tid < ncb && tid >= d) ? hist[tid - d] : 0;
        __syncthreads();
        if (tid < ncb && tid >= d) hist[tid] += t;
        __syncthreads();
    }

    // excl offsets, cursors, bulk global reservation, gofs = gres - excl
    int incl = 0, excl = 0;
    if (tid < ncb) { incl = hist[tid]; excl = tid ? hist[tid - 1] : 0; }
    __syncthreads();
    if (tid < ncb) {
        int cnt = incl - excl;
        cursor[tid] = excl;
        int gres = (cnt > 0) ? atomicAdd(&coarse_cnt[tid], cnt) : 0;
        hist[tid] = gres - excl;
    }
    __syncthreads();

    // scatter registers -> bin-sorted LDS stage
    for (int j = 0; j < ne; ++j) {
        int r, c; float v;
        if (j < EPC) { r = rr[j]; c = cc[j]; v = vv[j]; }
        else { int e = start + tid + j * 1024; r = rows[e]; c = cols[e]; v = vals[e]; }
        int bkt = r >> CRB_SHIFT;
        int pos = atomicAdd(&cursor[bkt], 1);
        stage[pos] = make_int2(((r & (CRB - 1)) << 17) | c, __float_as_int(v));
        sbkt[pos] = (unsigned short)bkt;
    }
    __syncthreads();

    // linear flush: consecutive lanes -> consecutive global addrs per run
    for (int i = tid; i < n; i += 1024) {
        int bkt = sbkt[i];
        int2 e = stage[i];
        int gidx = i + hist[bkt];          // = gres + (i - excl)
        if (gidx < ccap) {
            coarse[(size_t)bkt * ccap + gidx] = e;
        } else {
            int k = atomicAdd(ovf_cnt, 1);
            if (k < OVF_T) {
                int r = (bkt << CRB_SHIFT) | ((unsigned)e.x >> 17);
                ovf3[3 * k] = r; ovf3[3 * k + 1] = e.x & 0x1FFFF;
                ovf3[3 * k + 2] = e.y;
            }
        }
    }
}

// ---------------- pass 2: coarse bin -> 4 fine buckets (LDS counting sort) --
__global__ __launch_bounds__(1024) void p2_fine(
        const int* __restrict__ coarse_cnt,
        const int2* __restrict__ coarse,
        int* __restrict__ bucket_cnt,
        int2* __restrict__ packed,
        int* __restrict__ ovf_cnt,
        int* __restrict__ ovf3,
        int ccap, int cap, int nb) {
    __shared__ int2 stage[CCAP];
    __shared__ int hist4[4];
    __shared__ int loff[5];
    __shared__ int cur[4];

    int bin = blockIdx.x;
    int tid = threadIdx.x;
    int lane = tid & 63;
    int cnt = coarse_cnt[bin];
    if (cnt > ccap) cnt = ccap;
    const int2* cb = coarse + (size_t)bin * ccap;

    if (tid < 4) hist4[tid] = 0;

    int h0 = 0, h1 = 0, h2 = 0, h3 = 0;
    for (int i = tid; i < cnt; i += 1024) {
        int f = (cb[i].x >> 23) & 3;
        h0 += (f == 0); h1 += (f == 1); h2 += (f == 2); h3 += (f == 3);
    }
    for (int off = 32; off; off >>= 1) {
        h0 += __shfl_down(h0, off); h1 += __shfl_down(h1, off);
        h2 += __shfl_down(h2, off); h3 += __shfl_down(h3, off);
    }
    __syncthreads();
    if (lane == 0) {
        atomicAdd(&hist4[0], h0); atomicAdd(&hist4[1], h1);
        atomicAdd(&hist4[2], h2); atomicAdd(&hist4[3], h3);
    }
    __syncthreads();
    if (tid == 0) {
        int o = 0;
        for (int k = 0; k < 4; ++k) { loff[k] = o; cur[k] = o; o += hist4[k]; }
        loff[4] = o;
    }
    __syncthreads();

    for (int i = tid; i < cnt; i += 1024) {
        int2 e = cb[i];
        int f = (e.x >> 23) & 3;
        int p = 0;
        for (int k = 0; k < 4; ++k) {
            unsigned long long m = __ballot(f == k);
            if (f == k) {
                int leader = __ffsll((unsigned long long)m) - 1;
                int base = 0;
                if (lane == leader) base = atomicAdd(&cur[k], (int)__popcll(m));
                base = __shfl(base, leader);
                p = base + (int)__popcll(m & ((1ULL << lane) - 1ULL));
            }
        }
        stage[p] = e;
    }
    __syncthreads();

    int fb0 = bin << (CRB_SHIFT - RPB_SHIFT);
    for (int k = 0; k < 4; ++k) {
        int bkt = fb0 + k;
        if (bkt >= nb) break;
        int s = loff[k];
        int run = loff[k + 1] - s;
        int w = (run > cap) ? cap : run;
        for (int i = tid; i < w; i += 1024) {
            int2 e = stage[s + i];
            packed[(size_t)bkt * cap + i] = make_int2(e.x & 0x7FFFFF, e.y);
        }
        if (tid == 0) bucket_cnt[bkt] = w;
        for (int i = cap + tid; i < run; i += 1024) {
            int2 e = stage[s + i];
            int k2 = atomicAdd(ovf_cnt, 1);
            if (k2 < OVF_T) {
                int r = (bin << CRB_SHIFT) | ((unsigned)e.x >> 17);
                ovf3[3 * k2] = r; ovf3[3 * k2 + 1] = e.x & 0x1FFFF;
                ovf3[3 * k2 + 2] = e.y;
            }
        }
    }
}

// ---------------- phase 2: sort bucket by row, register-accumulate (v7) -----
template <bool HALF>
__global__ __launch_bounds__(256) void phase2_sort_gather(
        const int* __restrict__ bucket_cnt,
        const int2* __restrict__ packed,
        const __half* __restrict__ bh,
        const float* __restrict__ b,
        float* __restrict__ out,
        int cap, int N) {
    __shared__ int2 sorted[CAP_LDS];
    __shared__ int hist[RPB];
    __shared__ int offs[RPB + 1];
    __shared__ int cursor[RPB];

    int bucket = blockIdx.x;
    int tid = threadIdx.x;

    int cnt = bucket_cnt[bucket];
    if (cnt > cap) cnt = cap;
    const int2* pk = packed + (size_t)bucket * cap;

    if (tid < RPB) hist[tid] = 0;
    __syncthreads();

    int2 ev[EPT];
    int  rl[EPT];
    int ne = 0;
    for (int i = tid; i < cnt; i += 256) {
        int2 e = pk[i];
        ev[ne] = e;
        rl[ne] = ((unsigned)e.x) >> 17;
        atomicAdd(&hist[rl[ne]], 1);
        ++ne;
    }
    __syncthreads();

    for (int d = 1; d < RPB; d <<= 1) {
        int t = (tid < RPB && tid >= d) ? hist[tid - d] : 0;
        __syncthreads();
        if (tid < RPB) hist[tid] += t;
        __syncthreads();
    }
    if (tid == 0) offs[0] = 0;
    if (tid < RPB) {
        offs[tid + 1] = hist[tid];
        cursor[tid] = (tid == 0) ? 0 : hist[tid - 1];
    }
    __syncthreads();

    for (int j = 0; j < ne; ++j) {
        int pos = atomicAdd(&cursor[rl[j]], 1);
        sorted[pos] = make_int2(ev[j].x & 0x1FFFF, ev[j].y);
    }
    __syncthreads();

    int g = tid >> 5;
    int glane = tid & 31;
    int r0 = bucket << RPB_SHIFT;
    for (int k = 0; k < 8; ++k) {
        int rr = g * 8 + k;
        int start = offs[rr];
        int num = offs[rr + 1] - start;
        float4 acc = make_float4(0.f, 0.f, 0.f, 0.f);
        for (int base = 0; base < num; base += 8) {
#pragma unroll
            for (int j = 0; j < 8; ++j) {
                int idx = base + j;
                int sidx = start + ((idx < num) ? idx : (num - 1));
                int2 e = sorted[sidx];
                float v = (idx < num) ? __int_as_float(e.y) : 0.f;
                if (HALF) {
                    uint2 hv = ((const uint2*)(bh + (size_t)e.x * D_DIM))[glane];
                    __half2* hp = (__half2*)&hv;
                    float2 f0 = __half22float2(hp[0]);
                    float2 f1 = __half22float2(hp[1]);
                    acc.x += v * f0.x;
                    acc.y += v * f0.y;
                    acc.z += v * f1.x;
                    acc.w += v * f1.y;
                } else {
                    float4 bv = ((const float4*)(b + (size_t)e.x * D_DIM))[glane];
                    acc.x += v * bv.x;
                    acc.y += v * bv.y;
                    acc.z += v * bv.z;
                    acc.w += v * bv.w;
                }
            }
        }
        int r = r0 + rr;
        if (r < N) {
            fx4 av = {acc.x, acc.y, acc.z, acc.w};
            __builtin_nontemporal_store(av, (fx4*)(out + (size_t)r * D_DIM) + glane);
        }
    }
}

// ---------------- v7 fallback phase1 (triples spill) ------------------------
__global__ __launch_bounds__(1024) void phase1_partition(
        const int* __restrict__ rows,
        const int* __restrict__ cols,
        const float* __restrict__ vals,
        int* __restrict__ bucket_cnt,
        int2* __restrict__ packed,
        int* __restrict__ ovf_cnt,
        int* __restrict__ ovf3,
        int E, int nb, int cap, int chunk) {
    __shared__ int hist[MAXB];
    int tid = threadIdx.x;
    int start = blockIdx.x * chunk;
    int end = start + chunk; if (end > E) end = E;

    for (int i = tid; i < nb; i += 1024) hist[i] = 0;
    __syncthreads();

    int rr[EPT1]; int cc[EPT1]; float vv[EPT1];
    int ne = 0;
    for (int e = start + tid; e < end; e += 1024) {
        int r = rows[e];
        if (ne < EPT1) { rr[ne] = r; cc[ne] = cols[e]; vv[ne] = vals[e]; }
        ++ne;
        atomicAdd(&hist[r >> RPB_SHIFT], 1);
    }
    __syncthreads();

    for (int bkt = tid; bkt < nb; bkt += 1024) {
        int c = hist[bkt];
        hist[bkt] = (c > 0) ? atomicAdd(&bucket_cnt[bkt], c) : 0;
    }
    __syncthreads();

    int j = 0;
    for (int e = start + tid; e < end; e += 1024, ++j) {
        int r, c; float v;
        if (j < EPT1) { r = rr[j]; c = cc[j]; v = vv[j]; }
        else          { r = rows[e]; c = cols[e]; v = vals[e]; }
        int bkt = r >> RPB_SHIFT;
        int local = atomicAdd(&hist[bkt], 1);
        if (local < cap) {
            int key = ((r & (RPB - 1)) << 17) | c;
            packed[(size_t)bkt * cap + local] = make_int2(key, __float_as_int(v));
        } else {
            int k = atomicAdd(ovf_cnt, 1);
            if (k < OVF_T) {
                ovf3[3 * k] = r; ovf3[3 * k + 1] = c;
                ovf3[3 * k + 2] = __float_as_int(v);
            }
        }
    }
}

// ---------------- overflow fixup: (r,c,v) triples ---------------------------
__global__ void fixup_kernel(const int* __restrict__ ovf_cnt,
                             const int* __restrict__ ovf3,
                             const float* __restrict__ b,
                             float* __restrict__ out) {
    int items = *ovf_cnt;
    if (items > OVF_T) items = OVF_T;
    int gsz  = (gridDim.x * blockDim.x) >> 5;
    int gid  = (blockIdx.x * blockDim.x + threadIdx.x) >> 5;
    int lane = threadIdx.x & 31;
    for (int i = gid; i < items; i += gsz) {
        int r = ovf3[3 * i];
        int c = ovf3[3 * i + 1];
        float v = __int_as_float(ovf3[3 * i + 2]);
        float4 bv = ((const float4*)(b + (size_t)c * D_DIM))[lane];
        float* op = out + (size_t)r * D_DIM + (size_t)lane * 4;
        atomicAdd(op + 0, v * bv.x);
        atomicAdd(op + 1, v * bv.y);
        atomicAdd(op + 2, v * bv.z);
        atomicAdd(op + 3, v * bv.w);
    }
}

// ---------------- fallback (v1 atomic) ----------------
__global__ void spmm_atomic_kernel(const int* __restrict__ rows,
                                   const int* __restrict__ cols,
                                   const float* __restrict__ vals,
                                   const float* __restrict__ b,
                                   float* __restrict__ out, int E) {
    int t = blockIdx.x * blockDim.x + threadIdx.x;
    int e = t >> 5;
    if (e >= E) return;
    int lane = t & 31;
    int r = rows[e];
    int c = cols[e];
    float v = vals[e];
    float4 bv = ((const float4*)(b + (size_t)c * D_DIM))[lane];
    float* op = out + (size_t)r * D_DIM + (size_t)lane * 4;
    atomicAdd(op + 0, v * bv.x);
    atomicAdd(op + 1, v * bv.y);
    atomicAdd(op + 2, v * bv.z);
    atomicAdd(op + 3, v * bv.w);
}

extern "C" void kernel_launch(void* const* d_in, const int* in_sizes, int n_in,
                              void* d_out, int out_size, void* d_ws, size_t ws_size,
                              hipStream_t stream) {
    const int*   indices = (const int*)d_in[0];
    const float* vals    = (const float*)d_in[1];
    const float* b       = (const float*)d_in[3];
    float*       out     = (float*)d_out;

    int E = in_sizes[1];
    int N = out_size / D_DIM;
    const int* rows = indices;
    const int* cols = indices + E;

    int nb  = (N + RPB - 1) >> RPB_SHIFT;     // 1563
    int ncb = (N + CRB - 1) >> CRB_SHIFT;     // 391
    int avg  = (nb  > 0) ? E / nb  : 0;       // ~1023
    int cavg = (ncb > 0) ? E / ncb : 0;       // ~4092
    int cap = CAP_LDS;
    size_t bh_bytes = (size_t)N * D_DIM * 2;
    int n8 = N * D_DIM / 8;

    // ---- radix path (local-sort p1 + p2_fine) ----
    {
        bool ok = (ncb <= MAXCB) && (N <= 131072) &&
                  (cavg + cavg / 8 <= CCAP) && (cap > avg + avg / 8);
        size_t fixedN = (size_t)ncb * 4 + (size_t)nb * 4 + 4 + (size_t)OVF_T * 12;
        size_t pk_off = (fixedN + 255) & ~(size_t)255;
        size_t un_off = (pk_off + (size_t)nb * cap * 8 + 255) & ~(size_t)255;
        size_t coarse_bytes = (size_t)ncb * CCAP * 8;
        size_t un_bytes = coarse_bytes > bh_bytes ? coarse_bytes : bh_bytes;
        if (ok && ws_size >= un_off + un_bytes) {
            char* w = (char*)d_ws;
            int*    coarse_cnt = (int*)w;
            int*    bucket_cnt = (int*)(w + (size_t)ncb * 4);
            int*    ovf_cnt    = (int*)(w + (size_t)ncb * 4 + (size_t)nb * 4);
            int*    ovf3       = (int*)(w + (size_t)ncb * 4 + (size_t)nb * 4 + 4);
            int2*   packed     = (int2*)(w + pk_off);
            int2*   coarse     = (int2*)(w + un_off);
            __half* bh         = (__half*)(w + un_off);

            (void)hipMemsetAsync(coarse_cnt, 0,
                                 (size_t)ncb * 4 + (size_t)nb * 4 + 4, stream);

            int nwg1 = (E + CHUNK1 - 1) / CHUNK1;    // 391 @ E=1.6M
            p1_sortcoarse<<<nwg1, 1024, 0, stream>>>(
                rows, cols, vals, coarse_cnt, coarse, ovf_cnt, ovf3,
                E, ncb, CCAP);

            p2_fine<<<ncb, 1024, 0, stream>>>(
                coarse_cnt, coarse, bucket_cnt, packed, ovf_cnt, ovf3,
                CCAP, cap, nb);

            // bh overwrites coarse region (dead after p2_fine)
            convert_b_kernel<<<(n8 + 255) / 256, 256, 0, stream>>>(b, bh, n8);

            phase2_sort_gather<true><<<nb, 256, 0, stream>>>(
                bucket_cnt, packed, bh, b, out, cap, N);

            fixup_kernel<<<8, 256, 0, stream>>>(ovf_cnt, ovf3, b, out);
            return;
        }
    }

    // ---- v7 bucket-sort fallback ----
    size_t fixed      = (size_t)nb * 4 + 4 + (size_t)OVF_T * 12;
    size_t bh_off     = (fixed + 255) & ~(size_t)255;
    size_t packed_h   = (bh_off + bh_bytes + 255) & ~(size_t)255;  // fp16 layout
    size_t packed_f   = bh_off;                                    // fp32 layout
    size_t need_h     = packed_h + (size_t)nb * cap * 8;
    size_t need_f     = packed_f + (size_t)nb * cap * 8;

    bool okBase = (nb <= MAXB) && (N <= 131072) && (cap > avg + avg / 8);
    bool useHalf = okBase && (ws_size >= need_h);
    bool useF32  = okBase && !useHalf && (ws_size >= need_f);

    if (!useHalf && !useF32) {
        (void)hipMemsetAsync(d_out, 0, (size_t)out_size * sizeof(float), stream);
        long long total = (long long)E * 32;
        int blocks = (int)((total + 255) / 256);
        spmm_atomic_kernel<<<blocks, 256, 0, stream>>>(rows, cols, vals, b, out, E);
        return;
    }

    char* w = (char*)d_ws;
    int*    bucket_cnt = (int*)w;
    int*    ovf_cnt    = (int*)(w + (size_t)nb * 4);
    int*    ovf3       = (int*)(w + (size_t)nb * 4 + 4);
    __half* bh         = (__half*)(w + bh_off);
    int2*   packed     = (int2*)(w + (useHalf ? packed_h : packed_f));

    (void)hipMemsetAsync(bucket_cnt, 0, (size_t)nb * 4 + 4, stream);

    if (useHalf)
        convert_b_kernel<<<(n8 + 255) / 256, 256, 0, stream>>>(b, bh, n8);

    const int P1_WGS = 256;
    int chunk = (E + P1_WGS - 1) / P1_WGS;
    phase1_partition<<<P1_WGS, 1024, 0, stream>>>(
        rows, cols, vals, bucket_cnt, packed, ovf_cnt, ovf3, E, nb, cap, chunk);

    if (useHalf)
        phase2_sort_gather<true><<<nb, 256, 0, stream>>>(
            bucket_cnt, packed, bh, b, out, cap, N);
    else
        phase2_sort_gather<false><<<nb, 256, 0, stream>>>(
            bucket_cnt, packed, bh, b, out, cap, N);

    fixup_kernel<<<8, 256, 0, stream>>>(ovf_cnt, ovf3, b, out);
}